// Round 1
// baseline (837.319 us; speedup 1.0000x reference)
//
#include <hip/hip_runtime.h>
#include <math.h>

#define T_DIM 2048
#define N_B   2
#define C_DIM 1024
#define H_DIM 16
#define DH    64
#define M_DIM 4096
#define WIN   128
#define NEGI  -1e9f

// ---------------------------------------------------------------------------
// Projection GEMM: out[m,o] = sum_c X[m,c] * W[o,c] + bias[o]
//   X: (M, C) row-major      W: (C_out, C) row-major (accessed along rows = K)
// MODE 0: scatter into (N, H, T, Dh) head layout
// MODE 1: row-major (M, C) (used for the output projection -> d_out directly)
// Tile: 64x64, BK=16, 256 threads, 4x4 microtile per thread.
// ---------------------------------------------------------------------------
template<int MODE>
__global__ __launch_bounds__(256) void proj_gemm(
    const float* __restrict__ X, const float* __restrict__ W,
    const float* __restrict__ bias, float* __restrict__ out)
{
    __shared__ float As[16][68];   // [k][m], +4 pad keeps 16B alignment, 2-way banks
    __shared__ float Bs[16][68];   // [k][o]
    const int tid = threadIdx.x;
    const int m0 = blockIdx.x << 6;
    const int o0 = blockIdx.y << 6;
    const int tx = tid & 15;       // also k-offset on loads
    const int ty = tid >> 4;       // also row-group on loads

    float acc[4][4] = {};

    for (int k0 = 0; k0 < C_DIM; k0 += 16) {
        __syncthreads();
#pragma unroll
        for (int i = 0; i < 4; ++i) {
            As[tx][ty + 16*i] = X[(size_t)(m0 + ty + 16*i) * C_DIM + k0 + tx];
            Bs[tx][ty + 16*i] = W[(size_t)(o0 + ty + 16*i) * C_DIM + k0 + tx];
        }
        __syncthreads();
#pragma unroll
        for (int kk = 0; kk < 16; ++kk) {
            const float4 a = *(const float4*)&As[kk][ty << 2];
            const float4 b = *(const float4*)&Bs[kk][tx << 2];
            acc[0][0] += a.x*b.x; acc[0][1] += a.x*b.y; acc[0][2] += a.x*b.z; acc[0][3] += a.x*b.w;
            acc[1][0] += a.y*b.x; acc[1][1] += a.y*b.y; acc[1][2] += a.y*b.z; acc[1][3] += a.y*b.w;
            acc[2][0] += a.z*b.x; acc[2][1] += a.z*b.y; acc[2][2] += a.z*b.z; acc[2][3] += a.z*b.w;
            acc[3][0] += a.w*b.x; acc[3][1] += a.w*b.y; acc[3][2] += a.w*b.z; acc[3][3] += a.w*b.w;
        }
    }

    const float4 bv = *(const float4*)&bias[o0 + (tx << 2)];
    if (MODE == 0) {
        const int hh = o0 >> 6;             // o0 is a multiple of 64 = Dh
#pragma unroll
        for (int i = 0; i < 4; ++i) {
            const int m = m0 + (ty << 2) + i;
            const int t = m >> 1;           // m = t*N_B + n, N_B = 2
            const int nn = m & 1;
            float4 r4;
            r4.x = acc[i][0] + bv.x;
            r4.y = acc[i][1] + bv.y;
            r4.z = acc[i][2] + bv.z;
            r4.w = acc[i][3] + bv.w;
            *(float4*)&out[(((size_t)(nn * H_DIM + hh)) * T_DIM + t) * DH + (tx << 2)] = r4;
        }
    } else {
#pragma unroll
        for (int i = 0; i < 4; ++i) {
            const int m = m0 + (ty << 2) + i;
            float4 r4;
            r4.x = acc[i][0] + bv.x;
            r4.y = acc[i][1] + bv.y;
            r4.z = acc[i][2] + bv.z;
            r4.w = acc[i][3] + bv.w;
            *(float4*)&out[(size_t)m * C_DIM + o0 + (tx << 2)] = r4;
        }
    }
}

// ---------------------------------------------------------------------------
// Flash-style masked attention.
// Block: 256 threads = (query-group qg = tid>>2 : 64 groups x 2 queries) x
//        (quarter = tid&3 : 16 of the 64 dims).
// BQ = 128 queries per block, BK = 32 keys per tile.
// Mask: attend iff |i-j| <= WIN  or  j < key_length[n].
// Tile skip: keep iff k0 < kl or tile intersects [q0-WIN, q0+BQ-1+WIN].
// ---------------------------------------------------------------------------
__global__ __launch_bounds__(256) void attn_kernel(
    const float* __restrict__ QH, const float* __restrict__ KH,
    const float* __restrict__ VH, const int* __restrict__ key_length,
    float* __restrict__ Y)
{
    __shared__ float Ks[32][68];
    __shared__ float Vs[32][68];

    const int nh = blockIdx.x;           // 0..31  (n*16 + h)
    const int n  = nh >> 4;
    const int h  = nh & 15;
    const int q0 = blockIdx.y << 7;      // 128 queries per block
    const int kl = key_length[n];
    const int tid = threadIdx.x;
    const int quarter = tid & 3;
    const int qg = tid >> 2;             // 0..63
    const int i0 = q0 + (qg << 1);       // first of this thread's 2 queries
    const int dbase = quarter << 4;      // 16 dims per thread

    const size_t hb = (size_t)nh * T_DIM * DH;
    const float* Qb = QH + hb;
    const float* Kb = KH + hb;
    const float* Vb = VH + hb;

    // Q into registers
    float qreg[2][16];
#pragma unroll
    for (int ql = 0; ql < 2; ++ql)
#pragma unroll
        for (int w = 0; w < 4; ++w) {
            const float4 v = *(const float4*)&Qb[(size_t)(i0 + ql) * DH + dbase + (w << 2)];
            qreg[ql][w*4+0] = v.x; qreg[ql][w*4+1] = v.y;
            qreg[ql][w*4+2] = v.z; qreg[ql][w*4+3] = v.w;
        }

    float Oa[2][16] = {};
    float m_i[2] = {-INFINITY, -INFINITY};
    float l_i[2] = {0.f, 0.f};
    const float scale = 0.125f;          // 1/sqrt(Dh)

    const int lf = tid & 15, lr = tid >> 4;

    for (int k0 = 0; k0 < T_DIM; k0 += 32) {
        const bool band = (k0 <= q0 + 127 + WIN) && (k0 + 31 >= q0 - WIN);
        if (k0 >= kl && !band) continue;

        __syncthreads();
#pragma unroll
        for (int rr = lr; rr < 32; rr += 16) {
            *(float4*)&Ks[rr][lf << 2] = *(const float4*)&Kb[(size_t)(k0 + rr) * DH + (lf << 2)];
            *(float4*)&Vs[rr][lf << 2] = *(const float4*)&Vb[(size_t)(k0 + rr) * DH + (lf << 2)];
        }
        __syncthreads();

        // partial scores over this thread's 16 dims
        float s[2][32];
#pragma unroll
        for (int kj = 0; kj < 32; ++kj) {
            float p0 = 0.f, p1 = 0.f;
#pragma unroll
            for (int w = 0; w < 4; ++w) {
                const float4 kv = *(const float4*)&Ks[kj][dbase + (w << 2)];
                p0 += qreg[0][w*4+0]*kv.x + qreg[0][w*4+1]*kv.y
                    + qreg[0][w*4+2]*kv.z + qreg[0][w*4+3]*kv.w;
                p1 += qreg[1][w*4+0]*kv.x + qreg[1][w*4+1]*kv.y
                    + qreg[1][w*4+2]*kv.z + qreg[1][w*4+3]*kv.w;
            }
            s[0][kj] = p0; s[1][kj] = p1;
        }
        // reduce across the 4 quarter-lanes
#pragma unroll
        for (int ql = 0; ql < 2; ++ql)
#pragma unroll
            for (int kj = 0; kj < 32; ++kj) {
                float v = s[ql][kj];
                v += __shfl_xor(v, 1);
                v += __shfl_xor(v, 2);
                s[ql][kj] = v;
            }

        // mask + scale + online softmax update
#pragma unroll
        for (int ql = 0; ql < 2; ++ql) {
            const int i = i0 + ql;
            float mt = -INFINITY;
#pragma unroll
            for (int kj = 0; kj < 32; ++kj) {
                const int j = k0 + kj;
                const int dd = i - j;
                const bool ok = (dd <= WIN && dd >= -WIN) || (j < kl);
                const float v = ok ? s[ql][kj] * scale : NEGI;
                s[ql][kj] = v;
                mt = fmaxf(mt, v);
            }
            const float mnew = fmaxf(m_i[ql], mt);
            const float r = __expf(m_i[ql] - mnew);   // 0 on first tile
            m_i[ql] = mnew;
            float lsum = 0.f;
#pragma unroll
            for (int kj = 0; kj < 32; ++kj) {
                const float p = __expf(s[ql][kj] - mnew);
                s[ql][kj] = p;
                lsum += p;
            }
            l_i[ql] = l_i[ql] * r + lsum;
#pragma unroll
            for (int dd = 0; dd < 16; ++dd) Oa[ql][dd] *= r;
        }

        // PV accumulate
#pragma unroll
        for (int kj = 0; kj < 32; ++kj) {
#pragma unroll
            for (int w = 0; w < 4; ++w) {
                const float4 vv = *(const float4*)&Vs[kj][dbase + (w << 2)];
                Oa[0][w*4+0] += s[0][kj]*vv.x; Oa[0][w*4+1] += s[0][kj]*vv.y;
                Oa[0][w*4+2] += s[0][kj]*vv.z; Oa[0][w*4+3] += s[0][kj]*vv.w;
                Oa[1][w*4+0] += s[1][kj]*vv.x; Oa[1][w*4+1] += s[1][kj]*vv.y;
                Oa[1][w*4+2] += s[1][kj]*vv.z; Oa[1][w*4+3] += s[1][kj]*vv.w;
            }
        }
    }

    // epilogue: normalize and write to (M, C) row-major Y at column h*Dh
#pragma unroll
    for (int ql = 0; ql < 2; ++ql) {
        const float inv = 1.f / l_i[ql];
        const int i = i0 + ql;
        const size_t row = ((size_t)i * N_B + n) * C_DIM + h * DH + dbase;
#pragma unroll
        for (int w = 0; w < 4; ++w) {
            float4 o4;
            o4.x = Oa[ql][w*4+0] * inv;
            o4.y = Oa[ql][w*4+1] * inv;
            o4.z = Oa[ql][w*4+2] * inv;
            o4.w = Oa[ql][w*4+3] * inv;
            *(float4*)&Y[row + (w << 2)] = o4;
        }
    }
}

extern "C" void kernel_launch(void* const* d_in, const int* in_sizes, int n_in,
                              void* d_out, int out_size, void* d_ws, size_t ws_size,
                              hipStream_t stream) {
    const float* q  = (const float*)d_in[0];
    const float* k  = (const float*)d_in[1];
    const float* v  = (const float*)d_in[2];
    const float* Wq = (const float*)d_in[3];
    const float* bq = (const float*)d_in[4];
    const float* Wk = (const float*)d_in[5];
    const float* bk = (const float*)d_in[6];
    const float* Wv = (const float*)d_in[7];
    const float* bv = (const float*)d_in[8];
    const float* Wo = (const float*)d_in[9];
    const float* bo = (const float*)d_in[10];
    const int*   kl = (const int*)d_in[11];

    float* ws = (float*)d_ws;
    const size_t HSZ = (size_t)N_B * H_DIM * T_DIM * DH;  // 4M floats
    float* QH = ws;
    float* KH = ws + HSZ;
    float* VH = ws + 2 * HSZ;
    float* Yb = ws + 3 * HSZ;

    dim3 gp(M_DIM / 64, C_DIM / 64);
    proj_gemm<0><<<gp, 256, 0, stream>>>(q, Wq, bq, QH);
    proj_gemm<0><<<gp, 256, 0, stream>>>(k, Wk, bk, KH);
    proj_gemm<0><<<gp, 256, 0, stream>>>(v, Wv, bv, VH);

    attn_kernel<<<dim3(N_B * H_DIM, T_DIM / 128), 256, 0, stream>>>(QH, KH, VH, kl, Yb);

    proj_gemm<1><<<gp, 256, 0, stream>>>(Yb, Wo, bo, (float*)d_out);
}

// Round 2
// 154.837 us; speedup vs baseline: 5.4077x; 5.4077x over previous
//
#include <hip/hip_runtime.h>
#include <math.h>

#define T_DIM 2048
#define N_B   2
#define C_DIM 1024
#define H_DIM 16
#define DH    64
#define M_DIM 4096
#define WIN   128

typedef _Float16 h8 __attribute__((ext_vector_type(8)));
typedef float    f4 __attribute__((ext_vector_type(4)));

// ---------------------------------------------------------------------------
// async global->LDS, 16B per lane
// ---------------------------------------------------------------------------
__device__ __forceinline__ void glds16(const _Float16* g, _Float16* l) {
    typedef const __attribute__((address_space(1))) unsigned int guint;
    typedef __attribute__((address_space(3))) unsigned int luint;
    __builtin_amdgcn_global_load_lds((guint*)g, (luint*)l, 16, 0, 0);
}

// ---------------------------------------------------------------------------
// fp32 -> fp16 conversion prepass (7 arrays in one launch)
// ---------------------------------------------------------------------------
struct CvtA { const float* s; _Float16* d; int n; };
struct Cvt7 { CvtA a[7]; };

__global__ __launch_bounds__(256) void cvt_k(Cvt7 c) {
    CvtA A = c.a[blockIdx.y];
    const int i = (blockIdx.x * 256 + threadIdx.x) * 8;
    if (i >= A.n) return;
    const float4 v0 = *(const float4*)&A.s[i];
    const float4 v1 = *(const float4*)&A.s[i + 4];
    h8 o;
    o[0] = (_Float16)v0.x; o[1] = (_Float16)v0.y;
    o[2] = (_Float16)v0.z; o[3] = (_Float16)v0.w;
    o[4] = (_Float16)v1.x; o[5] = (_Float16)v1.y;
    o[6] = (_Float16)v1.z; o[7] = (_Float16)v1.w;
    *(h8*)&A.d[i] = o;
}

// ---------------------------------------------------------------------------
// fp16 MFMA GEMM: out[m,o] = sum_k A[m,k]*B[o,k] + bias[o]
// A: (4096,1024) fp16 row-major, B: (1024,1024) fp16 row-major (O,K)
// 128x128 tile, BK=32, 4 waves (2x2 quadrants of 64x64), global_load_lds.
// MODE 0: fp16 scatter into (N,H,T,Dh);  MODE 1: fp32 row-major (M,C)
// ---------------------------------------------------------------------------
template<int MODE>
__global__ __launch_bounds__(256) void proj16(
    const _Float16* __restrict__ A, const _Float16* __restrict__ B,
    const float* __restrict__ bias, void* __restrict__ outp)
{
    __shared__ _Float16 Asm[128 * 32];
    __shared__ _Float16 Bsm[128 * 32];
    const int tid  = threadIdx.x;
    const int lane = tid & 63;
    const int wave = tid >> 6;
    const int wr = wave >> 1, wc = wave & 1;
    const int l15 = lane & 15, hi = lane >> 4;
    const int m0 = blockIdx.x << 7;
    const int o0 = blockIdx.y << 7;

    f4 acc[4][4];
    const f4 z4 = {0.f, 0.f, 0.f, 0.f};
#pragma unroll
    for (int i = 0; i < 4; ++i)
#pragma unroll
        for (int j = 0; j < 4; ++j) acc[i][j] = z4;

    for (int k0 = 0; k0 < C_DIM; k0 += 32) {
        __syncthreads();
#pragma unroll
        for (int c = 0; c < 2; ++c) {
            const int chunk = tid + c * 256;          // 0..511, 8 halves each
            const int row = chunk >> 2, c8 = (chunk & 3) << 3;
            glds16(&A[(size_t)(m0 + row) * C_DIM + k0 + c8], &Asm[chunk << 3]);
            glds16(&B[(size_t)(o0 + row) * C_DIM + k0 + c8], &Bsm[chunk << 3]);
        }
        __syncthreads();

        h8 a[4], b[4];
#pragma unroll
        for (int mr = 0; mr < 4; ++mr)
            a[mr] = *(const h8*)&Asm[(wr * 64 + mr * 16 + l15) * 32 + hi * 8];
#pragma unroll
        for (int nf = 0; nf < 4; ++nf)
            b[nf] = *(const h8*)&Bsm[(wc * 64 + nf * 16 + l15) * 32 + hi * 8];
#pragma unroll
        for (int mr = 0; mr < 4; ++mr)
#pragma unroll
            for (int nf = 0; nf < 4; ++nf)
                acc[mr][nf] = __builtin_amdgcn_mfma_f32_16x16x32_f16(
                    a[mr], b[nf], acc[mr][nf], 0, 0, 0);
    }

#pragma unroll
    for (int nf = 0; nf < 4; ++nf) {
        const int o = o0 + wc * 64 + nf * 16 + l15;
        const float bb = bias[o];
        const int hh = o >> 6, d = o & 63;
#pragma unroll
        for (int mr = 0; mr < 4; ++mr)
#pragma unroll
            for (int reg = 0; reg < 4; ++reg) {
                const int m = m0 + wr * 64 + mr * 16 + 4 * hi + reg;
                const float val = acc[mr][nf][reg] + bb;
                if (MODE == 0) {
                    const int t = m >> 1, n = m & 1;
                    ((_Float16*)outp)[(((size_t)(n * H_DIM + hh)) * T_DIM + t) * DH + d] =
                        (_Float16)val;
                } else {
                    ((float*)outp)[(size_t)m * C_DIM + o] = val;
                }
            }
    }
}

// ---------------------------------------------------------------------------
// Flash attention, fp16 MFMA. Block = 4 waves, 128 q-rows (32/wave),
// K-tiles of 64 keys. Tile skip: prefix (k0 < kl) or band overlap.
// ---------------------------------------------------------------------------
__global__ __launch_bounds__(256) void attn_mfma(
    const _Float16* __restrict__ QH, const _Float16* __restrict__ KH,
    const _Float16* __restrict__ VH, const int* __restrict__ key_length,
    _Float16* __restrict__ Y)
{
    __shared__ _Float16 Ks[64][72];      // [key][d]
    __shared__ _Float16 Vt[64][72];      // [d][key]  (transposed)
    __shared__ _Float16 Ps[4][32][72];   // per-wave P tile [q][key]

    const int nh = blockIdx.x;
    const int n  = nh >> 4;
    const int h  = nh & 15;
    const int q0 = blockIdx.y << 7;
    const int kl = key_length[n];
    const int tid = threadIdx.x;
    const int lane = tid & 63;
    const int wave = tid >> 6;
    const int l15 = lane & 15, hi = lane >> 4;
    const int qw = q0 + wave * 32;

    const size_t hb = (size_t)nh * T_DIM * DH;
    const _Float16* Qb = QH + hb;
    const _Float16* Kb = KH + hb;
    const _Float16* Vb = VH + hb;

    // Q A-fragments: [m-frag][k-step]
    h8 qa[2][2];
#pragma unroll
    for (int mr = 0; mr < 2; ++mr)
#pragma unroll
        for (int ks = 0; ks < 2; ++ks)
            qa[mr][ks] = *(const h8*)&Qb[(size_t)(qw + mr * 16 + l15) * DH + ks * 32 + hi * 8];

    f4 O[2][4];
    const f4 z4 = {0.f, 0.f, 0.f, 0.f};
#pragma unroll
    for (int mr = 0; mr < 2; ++mr)
#pragma unroll
        for (int df = 0; df < 4; ++df) O[mr][df] = z4;
    float m_i[2][4], l_i[2][4];
#pragma unroll
    for (int mr = 0; mr < 2; ++mr)
#pragma unroll
        for (int r = 0; r < 4; ++r) { m_i[mr][r] = -1e30f; l_i[mr][r] = 0.f; }

    for (int k0 = 0; k0 < T_DIM; k0 += 64) {
        const bool band = (k0 <= q0 + 127 + WIN) && (k0 + 63 >= q0 - WIN);
        if (k0 >= kl && !band) continue;

        __syncthreads();
        // stage K tile (row-major) : 512 chunks of 8 halves
#pragma unroll
        for (int c = 0; c < 2; ++c) {
            const int idx = tid + c * 256;
            const int row = idx >> 3, c8 = (idx & 7) << 3;
            *(h8*)&Ks[row][c8] = *(const h8*)&Kb[(size_t)(k0 + row) * DH + c8];
        }
        // stage V transposed: lane owns d=lane, wave owns 16 keys
        {
            _Float16 tv[16];
#pragma unroll
            for (int j = 0; j < 16; ++j)
                tv[j] = Vb[(size_t)(k0 + wave * 16 + j) * DH + lane];
            *(h8*)&Vt[lane][wave * 16]     = *(h8*)&tv[0];
            *(h8*)&Vt[lane][wave * 16 + 8] = *(h8*)&tv[8];
        }
        __syncthreads();

        // S = Q K^T
        f4 sacc[2][4];
#pragma unroll
        for (int mr = 0; mr < 2; ++mr)
#pragma unroll
            for (int cf = 0; cf < 4; ++cf) sacc[mr][cf] = z4;
#pragma unroll
        for (int ks = 0; ks < 2; ++ks) {
            h8 kb[4];
#pragma unroll
            for (int cf = 0; cf < 4; ++cf)
                kb[cf] = *(const h8*)&Ks[cf * 16 + l15][ks * 32 + hi * 8];
#pragma unroll
            for (int mr = 0; mr < 2; ++mr)
#pragma unroll
                for (int cf = 0; cf < 4; ++cf)
                    sacc[mr][cf] = __builtin_amdgcn_mfma_f32_16x16x32_f16(
                        qa[mr][ks], kb[cf], sacc[mr][cf], 0, 0, 0);
        }

        // mask + online softmax (rows live across l15-lanes of same hi-group)
#pragma unroll
        for (int mr = 0; mr < 2; ++mr) {
            float sv[4][4];
#pragma unroll
            for (int cf = 0; cf < 4; ++cf)
#pragma unroll
                for (int reg = 0; reg < 4; ++reg) {
                    const int i = qw + mr * 16 + 4 * hi + reg;
                    const int j = k0 + cf * 16 + l15;
                    const int dd = i - j;
                    const bool ok = (dd <= WIN && dd >= -WIN) || (j < kl);
                    sv[cf][reg] = ok ? sacc[mr][cf][reg] * 0.125f : -1e9f;
                }
#pragma unroll
            for (int reg = 0; reg < 4; ++reg) {
                float mt = fmaxf(fmaxf(sv[0][reg], sv[1][reg]),
                                 fmaxf(sv[2][reg], sv[3][reg]));
                mt = fmaxf(mt, __shfl_xor(mt, 1));
                mt = fmaxf(mt, __shfl_xor(mt, 2));
                mt = fmaxf(mt, __shfl_xor(mt, 4));
                mt = fmaxf(mt, __shfl_xor(mt, 8));
                const float mnew = fmaxf(m_i[mr][reg], mt);
                const float rr = __expf(m_i[mr][reg] - mnew);
                m_i[mr][reg] = mnew;
                float ls = 0.f;
#pragma unroll
                for (int cf = 0; cf < 4; ++cf) {
                    const float p = __expf(sv[cf][reg] - mnew);
                    ls += p;
                    Ps[wave][mr * 16 + 4 * hi + reg][cf * 16 + l15] = (_Float16)p;
                }
                ls += __shfl_xor(ls, 1); ls += __shfl_xor(ls, 2);
                ls += __shfl_xor(ls, 4); ls += __shfl_xor(ls, 8);
                l_i[mr][reg] = l_i[mr][reg] * rr + ls;
#pragma unroll
                for (int df = 0; df < 4; ++df) O[mr][df][reg] *= rr;
            }
        }

        // O += P V
#pragma unroll
        for (int ks = 0; ks < 2; ++ks) {
            h8 pa[2], vb[4];
#pragma unroll
            for (int mr = 0; mr < 2; ++mr)
                pa[mr] = *(const h8*)&Ps[wave][mr * 16 + l15][ks * 32 + hi * 8];
#pragma unroll
            for (int df = 0; df < 4; ++df)
                vb[df] = *(const h8*)&Vt[df * 16 + l15][ks * 32 + hi * 8];
#pragma unroll
            for (int mr = 0; mr < 2; ++mr)
#pragma unroll
                for (int df = 0; df < 4; ++df)
                    O[mr][df] = __builtin_amdgcn_mfma_f32_16x16x32_f16(
                        pa[mr], vb[df], O[mr][df], 0, 0, 0);
        }
    }

    // epilogue -> Y fp16, row m = i*2+n, col h*64+d
#pragma unroll
    for (int mr = 0; mr < 2; ++mr)
#pragma unroll
        for (int reg = 0; reg < 4; ++reg) {
            const float inv = 1.f / l_i[mr][reg];
            const int i = qw + mr * 16 + 4 * hi + reg;
#pragma unroll
            for (int df = 0; df < 4; ++df) {
                const int d = df * 16 + l15;
                Y[((size_t)i * N_B + n) * C_DIM + h * DH + d] =
                    (_Float16)(O[mr][df][reg] * inv);
            }
        }
}

extern "C" void kernel_launch(void* const* d_in, const int* in_sizes, int n_in,
                              void* d_out, int out_size, void* d_ws, size_t ws_size,
                              hipStream_t stream) {
    const float* q  = (const float*)d_in[0];
    const float* k  = (const float*)d_in[1];
    const float* v  = (const float*)d_in[2];
    const float* Wq = (const float*)d_in[3];
    const float* bq = (const float*)d_in[4];
    const float* Wk = (const float*)d_in[5];
    const float* bk = (const float*)d_in[6];
    const float* Wv = (const float*)d_in[7];
    const float* bv = (const float*)d_in[8];
    const float* Wo = (const float*)d_in[9];
    const float* bo = (const float*)d_in[10];
    const int*   kl = (const int*)d_in[11];

    const int NX = M_DIM * C_DIM;   // 4194304
    const int NW = C_DIM * C_DIM;   // 1048576

    _Float16* xq = (_Float16*)d_ws;
    _Float16* xk = xq + NX;
    _Float16* xv = xk + NX;
    _Float16* wq = xv + NX;
    _Float16* wk = wq + NW;
    _Float16* wv = wk + NW;
    _Float16* wo = wv + NW;
    _Float16* QHh = wo + NW;
    _Float16* KHh = QHh + NX;
    _Float16* VHh = KHh + NX;
    _Float16* Yh  = xq;             // reuse xq after Q projection

    Cvt7 c;
    c.a[0] = {q,  xq, NX}; c.a[1] = {k,  xk, NX}; c.a[2] = {v,  xv, NX};
    c.a[3] = {Wq, wq, NW}; c.a[4] = {Wk, wk, NW};
    c.a[5] = {Wv, wv, NW}; c.a[6] = {Wo, wo, NW};
    cvt_k<<<dim3(NX / (256 * 8), 7), 256, 0, stream>>>(c);

    dim3 gp(M_DIM / 128, C_DIM / 128);
    proj16<0><<<gp, 256, 0, stream>>>(xq, wq, bq, QHh);
    proj16<0><<<gp, 256, 0, stream>>>(xk, wk, bk, KHh);
    proj16<0><<<gp, 256, 0, stream>>>(xv, wv, bv, VHh);

    attn_mfma<<<dim3(N_B * H_DIM, T_DIM / 128), 256, 0, stream>>>(QHh, KHh, VHh, kl, Yh);

    proj16<1><<<gp, 256, 0, stream>>>(Yh, wo, bo, (float*)d_out);
}

// Round 4
// 128.490 us; speedup vs baseline: 6.5166x; 1.2051x over previous
//
#include <hip/hip_runtime.h>
#include <math.h>

#define T_DIM 2048
#define N_B   2
#define C_DIM 1024
#define H_DIM 16
#define DH    64
#define M_DIM 4096
#define WIN   128

typedef _Float16 h8 __attribute__((ext_vector_type(8)));
typedef float    f4 __attribute__((ext_vector_type(4)));

#if __has_builtin(__builtin_amdgcn_exp2f)
#define EXP2(x) __builtin_amdgcn_exp2f(x)
#else
#define EXP2(x) __expf((x) * 0.693147180559945f)
#endif

// ---------------------------------------------------------------------------
// async global->LDS, 16B per lane
// ---------------------------------------------------------------------------
__device__ __forceinline__ void glds16(const _Float16* g, _Float16* l) {
    typedef const __attribute__((address_space(1))) unsigned int guint;
    typedef __attribute__((address_space(3))) unsigned int luint;
    __builtin_amdgcn_global_load_lds((guint*)g, (luint*)l, 16, 0, 0);
}

// ---------------------------------------------------------------------------
// fp32 -> fp16 conversion prepass (7 arrays in one launch)
// ---------------------------------------------------------------------------
struct CvtA { const float* s; _Float16* d; int n; };
struct Cvt7 { CvtA a[7]; };

__global__ __launch_bounds__(256) void cvt_k(Cvt7 c) {
    CvtA A = c.a[blockIdx.y];
    const int i = (blockIdx.x * 256 + threadIdx.x) * 8;
    if (i >= A.n) return;
    const float4 v0 = *(const float4*)&A.s[i];
    const float4 v1 = *(const float4*)&A.s[i + 4];
    h8 o;
    o[0] = (_Float16)v0.x; o[1] = (_Float16)v0.y;
    o[2] = (_Float16)v0.z; o[3] = (_Float16)v0.w;
    o[4] = (_Float16)v1.x; o[5] = (_Float16)v1.y;
    o[6] = (_Float16)v1.z; o[7] = (_Float16)v1.w;
    *(h8*)&A.d[i] = o;
}

// ---------------------------------------------------------------------------
// Fused Q/K/V projection: z = blockIdx.z picks {x, W, b, out}.
// out[m,o] = sum_k X[m,k]*W[o,k] + b[o]
// z in {0,1}: fp16 scatter into (N,H,T,Dh).  z == 2: fp16 scatter into
// (N,H,Dh,T) (transposed heads) so attention reads V^T rows contiguously.
// 128x128 tile, BK=32, 4 waves (2x2 quadrants of 64x64), global_load_lds.
// ---------------------------------------------------------------------------
struct QkvArgs {
    const _Float16* x[3];
    const _Float16* w[3];
    const float*    b[3];
    _Float16*       out[3];
};

__global__ __launch_bounds__(256) void proj_qkv(QkvArgs args) {
    const int z = blockIdx.z;
    const _Float16* __restrict__ A = args.x[z];
    const _Float16* __restrict__ B = args.w[z];
    const float* __restrict__ bias = args.b[z];
    _Float16* __restrict__ out     = args.out[z];

    __shared__ _Float16 Asm[128 * 32];
    __shared__ _Float16 Bsm[128 * 32];
    const int tid  = threadIdx.x;
    const int lane = tid & 63;
    const int wave = tid >> 6;
    const int wr = wave >> 1, wc = wave & 1;
    const int l15 = lane & 15, hi = lane >> 4;
    const int m0 = blockIdx.x << 7;
    const int o0 = blockIdx.y << 7;

    f4 acc[4][4];
    const f4 z4 = {0.f, 0.f, 0.f, 0.f};
#pragma unroll
    for (int i = 0; i < 4; ++i)
#pragma unroll
        for (int j = 0; j < 4; ++j) acc[i][j] = z4;

    for (int k0 = 0; k0 < C_DIM; k0 += 32) {
        __syncthreads();
#pragma unroll
        for (int c = 0; c < 2; ++c) {
            const int chunk = tid + c * 256;
            const int row = chunk >> 2, c8 = (chunk & 3) << 3;
            glds16(&A[(size_t)(m0 + row) * C_DIM + k0 + c8], &Asm[chunk << 3]);
            glds16(&B[(size_t)(o0 + row) * C_DIM + k0 + c8], &Bsm[chunk << 3]);
        }
        __syncthreads();

        h8 a[4], b[4];
#pragma unroll
        for (int mr = 0; mr < 4; ++mr)
            a[mr] = *(const h8*)&Asm[(wr * 64 + mr * 16 + l15) * 32 + hi * 8];
#pragma unroll
        for (int nf = 0; nf < 4; ++nf)
            b[nf] = *(const h8*)&Bsm[(wc * 64 + nf * 16 + l15) * 32 + hi * 8];
#pragma unroll
        for (int mr = 0; mr < 4; ++mr)
#pragma unroll
            for (int nf = 0; nf < 4; ++nf)
                acc[mr][nf] = __builtin_amdgcn_mfma_f32_16x16x32_f16(
                    a[mr], b[nf], acc[mr][nf], 0, 0, 0);
    }

#pragma unroll
    for (int nf = 0; nf < 4; ++nf) {
        const int o = o0 + wc * 64 + nf * 16 + l15;
        const float bb = bias[o];
        const int hh = o >> 6, d = o & 63;
#pragma unroll
        for (int mr = 0; mr < 4; ++mr)
#pragma unroll
            for (int reg = 0; reg < 4; ++reg) {
                const int m = m0 + wr * 64 + mr * 16 + 4 * hi + reg;
                const float val = acc[mr][nf][reg] + bb;
                const int t = m >> 1, n = m & 1;
                if (z == 2) {
                    out[(((size_t)(n * H_DIM + hh)) * DH + d) * T_DIM + t] = (_Float16)val;
                } else {
                    out[(((size_t)(n * H_DIM + hh)) * T_DIM + t) * DH + d] = (_Float16)val;
                }
            }
    }
}

// ---------------------------------------------------------------------------
// Output projection: fp16 A (M,C) x fp16 Wo (C,C) -> fp32 (M,C) = d_out
// ---------------------------------------------------------------------------
__global__ __launch_bounds__(256) void proj_o(
    const _Float16* __restrict__ A, const _Float16* __restrict__ B,
    const float* __restrict__ bias, float* __restrict__ out)
{
    __shared__ _Float16 Asm[128 * 32];
    __shared__ _Float16 Bsm[128 * 32];
    const int tid  = threadIdx.x;
    const int lane = tid & 63;
    const int wave = tid >> 6;
    const int wr = wave >> 1, wc = wave & 1;
    const int l15 = lane & 15, hi = lane >> 4;
    const int m0 = blockIdx.x << 7;
    const int o0 = blockIdx.y << 7;

    f4 acc[4][4];
    const f4 z4 = {0.f, 0.f, 0.f, 0.f};
#pragma unroll
    for (int i = 0; i < 4; ++i)
#pragma unroll
        for (int j = 0; j < 4; ++j) acc[i][j] = z4;

    for (int k0 = 0; k0 < C_DIM; k0 += 32) {
        __syncthreads();
#pragma unroll
        for (int c = 0; c < 2; ++c) {
            const int chunk = tid + c * 256;
            const int row = chunk >> 2, c8 = (chunk & 3) << 3;
            glds16(&A[(size_t)(m0 + row) * C_DIM + k0 + c8], &Asm[chunk << 3]);
            glds16(&B[(size_t)(o0 + row) * C_DIM + k0 + c8], &Bsm[chunk << 3]);
        }
        __syncthreads();

        h8 a[4], b[4];
#pragma unroll
        for (int mr = 0; mr < 4; ++mr)
            a[mr] = *(const h8*)&Asm[(wr * 64 + mr * 16 + l15) * 32 + hi * 8];
#pragma unroll
        for (int nf = 0; nf < 4; ++nf)
            b[nf] = *(const h8*)&Bsm[(wc * 64 + nf * 16 + l15) * 32 + hi * 8];
#pragma unroll
        for (int mr = 0; mr < 4; ++mr)
#pragma unroll
            for (int nf = 0; nf < 4; ++nf)
                acc[mr][nf] = __builtin_amdgcn_mfma_f32_16x16x32_f16(
                    a[mr], b[nf], acc[mr][nf], 0, 0, 0);
    }

#pragma unroll
    for (int nf = 0; nf < 4; ++nf) {
        const int o = o0 + wc * 64 + nf * 16 + l15;
        const float bb = bias[o];
#pragma unroll
        for (int mr = 0; mr < 4; ++mr)
#pragma unroll
            for (int reg = 0; reg < 4; ++reg) {
                const int m = m0 + wr * 64 + mr * 16 + 4 * hi + reg;
                out[(size_t)m * C_DIM + o] = acc[mr][nf][reg] + bb;
            }
    }
}

// ---------------------------------------------------------------------------
// Flash attention v4: one wave per block, 32 q-rows per wave, 64-key tiles.
// No K/V LDS staging (K/V per head = 256 KB -> L2-resident); B-frags read
// directly from global. V comes from the transposed (N,H,Dh,T) buffer.
// LDS only for the per-wave P routing tile. No __syncthreads anywhere.
// ---------------------------------------------------------------------------
__global__ __launch_bounds__(64) void attn_v4(
    const _Float16* __restrict__ QH, const _Float16* __restrict__ KH,
    const _Float16* __restrict__ VT, const int* __restrict__ key_length,
    _Float16* __restrict__ Y)
{
    __shared__ _Float16 Ps[32][72];

    const int nh = blockIdx.x;
    const int n  = nh >> 4;
    const int h  = nh & 15;
    const int qw = blockIdx.y << 5;          // 32 query rows per wave
    const int kl = key_length[n];
    const int lane = threadIdx.x;
    const int l15 = lane & 15, hi = lane >> 4;

    const size_t hb = (size_t)nh * T_DIM * DH;
    const _Float16* Qb = QH + hb;
    const _Float16* Kb = KH + hb;
    const _Float16* Vb = VT + hb;            // [d][t] within this head

    // Q A-fragments
    h8 qa[2][2];
#pragma unroll
    for (int mr = 0; mr < 2; ++mr)
#pragma unroll
        for (int ks = 0; ks < 2; ++ks)
            qa[mr][ks] = *(const h8*)&Qb[(size_t)(qw + mr * 16 + l15) * DH + ks * 32 + hi * 8];

    f4 O[2][4];
    const f4 z4 = {0.f, 0.f, 0.f, 0.f};
#pragma unroll
    for (int mr = 0; mr < 2; ++mr)
#pragma unroll
        for (int df = 0; df < 4; ++df) O[mr][df] = z4;
    float m_i[2][4], l_i[2][4];
#pragma unroll
    for (int mr = 0; mr < 2; ++mr)
#pragma unroll
        for (int r = 0; r < 4; ++r) { m_i[mr][r] = -1e30f; l_i[mr][r] = 0.f; }

    const float SC = 0.18033688f;            // (1/sqrt(64)) * log2(e)

    for (int k0 = 0; k0 < T_DIM; k0 += 64) {
        // keep iff any (i,j) in this wave's rows x tile is unmasked
        const bool keep = (k0 < kl) || (k0 <= qw + 31 + WIN && k0 + 63 >= qw - WIN);
        if (!keep) continue;
        // fully unmasked? prefix covers the tile, or the band covers ALL
        // 32x64 (i,j) pairs:  max(i-j)=qw+31-k0 <= WIN  AND  max(j-i)=k0+63-qw <= WIN
        const bool full = (k0 + 63 < kl) ||
                          (k0 >= qw + 31 - WIN && k0 + 63 <= qw + WIN);

        // K fragments straight from L2
        h8 kb[2][4];
#pragma unroll
        for (int ks = 0; ks < 2; ++ks)
#pragma unroll
            for (int cf = 0; cf < 4; ++cf)
                kb[ks][cf] = *(const h8*)&Kb[(size_t)(k0 + cf * 16 + l15) * DH + ks * 32 + hi * 8];

        // S = Q K^T
        f4 sacc[2][4];
#pragma unroll
        for (int mr = 0; mr < 2; ++mr)
#pragma unroll
            for (int cf = 0; cf < 4; ++cf) sacc[mr][cf] = z4;
#pragma unroll
        for (int ks = 0; ks < 2; ++ks)
#pragma unroll
            for (int mr = 0; mr < 2; ++mr)
#pragma unroll
                for (int cf = 0; cf < 4; ++cf)
                    sacc[mr][cf] = __builtin_amdgcn_mfma_f32_16x16x32_f16(
                        qa[mr][ks], kb[ks][cf], sacc[mr][cf], 0, 0, 0);

        // V fragments issued now; latency hides under softmax
        h8 vb[2][4];
#pragma unroll
        for (int ks = 0; ks < 2; ++ks)
#pragma unroll
            for (int df = 0; df < 4; ++df)
                vb[ks][df] = *(const h8*)&Vb[(size_t)(df * 16 + l15) * T_DIM + k0 + ks * 32 + hi * 8];

        // online softmax (exp2 domain); rows (mr, 4*hi+reg), cols in l15 lanes
#pragma unroll
        for (int mr = 0; mr < 2; ++mr) {
            float sv[4][4];
            if (full) {
#pragma unroll
                for (int cf = 0; cf < 4; ++cf)
#pragma unroll
                    for (int reg = 0; reg < 4; ++reg)
                        sv[cf][reg] = sacc[mr][cf][reg] * SC;
            } else {
#pragma unroll
                for (int cf = 0; cf < 4; ++cf)
#pragma unroll
                    for (int reg = 0; reg < 4; ++reg) {
                        const int i = qw + mr * 16 + 4 * hi + reg;
                        const int j = k0 + cf * 16 + l15;
                        const int dd = i - j;
                        const bool ok = (dd <= WIN && dd >= -WIN) || (j < kl);
                        sv[cf][reg] = ok ? sacc[mr][cf][reg] * SC : -1e9f;
                    }
            }
#pragma unroll
            for (int reg = 0; reg < 4; ++reg) {
                float mt = fmaxf(fmaxf(sv[0][reg], sv[1][reg]),
                                 fmaxf(sv[2][reg], sv[3][reg]));
                mt = fmaxf(mt, __shfl_xor(mt, 1));
                mt = fmaxf(mt, __shfl_xor(mt, 2));
                mt = fmaxf(mt, __shfl_xor(mt, 4));
                mt = fmaxf(mt, __shfl_xor(mt, 8));
                const float mnew = fmaxf(m_i[mr][reg], mt);
                const float rr = EXP2(m_i[mr][reg] - mnew);
                m_i[mr][reg] = mnew;
                float ls = 0.f;
#pragma unroll
                for (int cf = 0; cf < 4; ++cf) {
                    const float p = EXP2(sv[cf][reg] - mnew);
                    ls += p;
                    Ps[mr * 16 + 4 * hi + reg][cf * 16 + l15] = (_Float16)p;
                }
                ls += __shfl_xor(ls, 1); ls += __shfl_xor(ls, 2);
                ls += __shfl_xor(ls, 4); ls += __shfl_xor(ls, 8);
                l_i[mr][reg] = l_i[mr][reg] * rr + ls;
#pragma unroll
                for (int df = 0; df < 4; ++df) O[mr][df][reg] *= rr;
            }
        }

        // O += P V
        h8 pa[2][2];
#pragma unroll
        for (int mr = 0; mr < 2; ++mr)
#pragma unroll
            for (int ks = 0; ks < 2; ++ks)
                pa[mr][ks] = *(const h8*)&Ps[mr * 16 + l15][ks * 32 + hi * 8];
#pragma unroll
        for (int ks = 0; ks < 2; ++ks)
#pragma unroll
            for (int mr = 0; mr < 2; ++mr)
#pragma unroll
                for (int df = 0; df < 4; ++df)
                    O[mr][df] = __builtin_amdgcn_mfma_f32_16x16x32_f16(
                        pa[mr][ks], vb[ks][df], O[mr][df], 0, 0, 0);
    }

    // epilogue -> Y fp16 (M, C) at row i*2+n, col h*64+d
#pragma unroll
    for (int mr = 0; mr < 2; ++mr)
#pragma unroll
        for (int reg = 0; reg < 4; ++reg) {
            const float inv = 1.f / l_i[mr][reg];
            const int i = qw + mr * 16 + 4 * hi + reg;
#pragma unroll
            for (int df = 0; df < 4; ++df) {
                Y[((size_t)i * N_B + n) * C_DIM + h * DH + df * 16 + l15] =
                    (_Float16)(O[mr][df][reg] * inv);
            }
        }
}

extern "C" void kernel_launch(void* const* d_in, const int* in_sizes, int n_in,
                              void* d_out, int out_size, void* d_ws, size_t ws_size,
                              hipStream_t stream) {
    const float* q  = (const float*)d_in[0];
    const float* k  = (const float*)d_in[1];
    const float* v  = (const float*)d_in[2];
    const float* Wq = (const float*)d_in[3];
    const float* bq = (const float*)d_in[4];
    const float* Wk = (const float*)d_in[5];
    const float* bk = (const float*)d_in[6];
    const float* Wv = (const float*)d_in[7];
    const float* bv = (const float*)d_in[8];
    const float* Wo = (const float*)d_in[9];
    const float* bo = (const float*)d_in[10];
    const int*   kl = (const int*)d_in[11];

    const int NX = M_DIM * C_DIM;   // 4194304
    const int NW = C_DIM * C_DIM;   // 1048576

    _Float16* xq = (_Float16*)d_ws;
    _Float16* xk = xq + NX;
    _Float16* xv = xk + NX;
    _Float16* wq = xv + NX;
    _Float16* wk = wq + NW;
    _Float16* wv = wk + NW;
    _Float16* wo = wv + NW;
    _Float16* QHh = wo + NW;
    _Float16* KHh = QHh + NX;
    _Float16* VTh = KHh + NX;
    _Float16* Yh  = xq;             // reuse xq after projections

    Cvt7 c;
    c.a[0] = {q,  xq, NX}; c.a[1] = {k,  xk, NX}; c.a[2] = {v,  xv, NX};
    c.a[3] = {Wq, wq, NW}; c.a[4] = {Wk, wk, NW};
    c.a[5] = {Wv, wv, NW}; c.a[6] = {Wo, wo, NW};
    cvt_k<<<dim3(NX / (256 * 8), 7), 256, 0, stream>>>(c);

    QkvArgs qa;
    qa.x[0] = xq; qa.x[1] = xk; qa.x[2] = xv;
    qa.w[0] = wq; qa.w[1] = wk; qa.w[2] = wv;
    qa.b[0] = bq; qa.b[1] = bk; qa.b[2] = bv;
    qa.out[0] = QHh; qa.out[1] = KHh; qa.out[2] = VTh;
    proj_qkv<<<dim3(M_DIM / 128, C_DIM / 128, 3), 256, 0, stream>>>(qa);

    attn_v4<<<dim3(N_B * H_DIM, T_DIM / 32), 64, 0, stream>>>(QHh, KHh, VTh, kl, Yh);

    proj_o<<<dim3(M_DIM / 128, C_DIM / 128), 256, 0, stream>>>(Yh, wo, bo, (float*)d_out);
}